// Round 14
// baseline (71.275 us; speedup 1.0000x reference)
//
#include <hip/hip_runtime.h>

typedef __attribute__((ext_vector_type(8))) short short8;
typedef __attribute__((ext_vector_type(4))) float f32x4;

constexpr int BATCH = 4;
constexpr int SEQ   = 512;
constexpr int DM    = 256;

#define MFMA(a,b,c) __builtin_amdgcn_mfma_f32_16x16x32_bf16((a),(b),(c),0,0,0)

// ---------------------------------------------------------------------------
__device__ __forceinline__ unsigned short bf16h(float x) {
    unsigned u = __float_as_uint(x);
    return (unsigned short)((u + 0x7FFF + ((u >> 16) & 1)) >> 16);  // RNE
}
__device__ __forceinline__ float bf16f(unsigned short h) {
    return __uint_as_float(((unsigned)h) << 16);
}
__device__ __forceinline__ float exp2x_clamped(float x) {
    x = fminf(5.0f, fmaxf(-5.0f, x));
    return __builtin_amdgcn_exp2f(x * 2.8853900817779268f); // exp(2x)
}
__device__ __forceinline__ void cvt8(const float* s, int4& h, int4& l) {
    unsigned hw[8], lw[8];
    #pragma unroll
    for (int j = 0; j < 8; ++j) {
        unsigned short hb = bf16h(s[j]);
        hw[j] = hb;
        lw[j] = bf16h(s[j] - bf16f(hb));
    }
    h.x = (int)(hw[0] | (hw[1] << 16)); h.y = (int)(hw[2] | (hw[3] << 16));
    h.z = (int)(hw[4] | (hw[5] << 16)); h.w = (int)(hw[6] | (hw[7] << 16));
    l.x = (int)(lw[0] | (lw[1] << 16)); l.y = (int)(lw[2] | (lw[3] << 16));
    l.z = (int)(lw[4] | (lw[5] << 16)); l.w = (int)(lw[6] | (lw[7] << 16));
}

// ---------------------------------------------------------------------------
// f32 -> bf16 hi/lo pre-conversion for q,k,v and the 4 weight matrices,
// plus (y==7) zeroing of the 2048-entry rowsum accumulator (every call,
// graph-replay safe).
__global__ __launch_bounds__(256) void conv_kernel(
    const float* __restrict__ q, const float* __restrict__ k, const float* __restrict__ v,
    const float* __restrict__ Wq, const float* __restrict__ Wk,
    const float* __restrict__ Wv, const float* __restrict__ Wo,
    ushort* qh, ushort* ql, ushort* kh, ushort* kl, ushort* vh, ushort* vl,
    ushort* Wqh, ushort* Wql, ushort* Wkh, ushort* Wkl,
    ushort* Wvh, ushort* Wvl, ushort* Woh, ushort* Wol,
    float* rowsum)
{
    if (blockIdx.y == 7) {
        int idx = blockIdx.x * 256 + threadIdx.x;
        if (idx < BATCH * SEQ) rowsum[idx] = 0.f;
        return;
    }
    const float* s; ushort* h; ushort* l; int n;
    switch (blockIdx.y) {
        case 0: s = q;  h = qh;  l = ql;  n = 524288; break;
        case 1: s = k;  h = kh;  l = kl;  n = 524288; break;
        case 2: s = v;  h = vh;  l = vl;  n = 524288; break;
        case 3: s = Wq; h = Wqh; l = Wql; n = 65536;  break;
        case 4: s = Wk; h = Wkh; l = Wkl; n = 65536;  break;
        case 5: s = Wv; h = Wvh; l = Wvl; n = 65536;  break;
        default:s = Wo; h = Woh; l = Wol; n = 65536;  break;
    }
    int idx = (blockIdx.x * 256 + threadIdx.x) * 8;
    if (idx >= n) return;
    float4 f0 = *(const float4*)(s + idx);
    float4 f1 = *(const float4*)(s + idx + 4);
    float xs[8] = {f0.x, f0.y, f0.z, f0.w, f1.x, f1.y, f1.z, f1.w};
    int4 ph, pl;
    cvt8(xs, ph, pl);
    *(int4*)&h[idx] = ph;
    *(int4*)&l[idx] = pl;
}

// ---------------------------------------------------------------------------
// MFMA GEMM core (round-5 proven single-buffer structure), K=256 fixed.
// C[m][n] = sum_k A[m][k]*B[n][k]; f32 as bf16 hi/lo, 3 passes (hh+hl+lh).
// Tile 64x64, 4 waves (2x2), LDS frag-linear chunk order.
// EPI: 0 = f32 C = exp(2(x+bias)); 1 = bf16 h/l TRANSPOSED out (+bias);
//      2 = f32 C = x + bias.
// ASRC: 0 = A from bf16 h/l; 4 = A from sum of FOUR f32 arrays (inline cvt).
template<int EPI, int ASRC>
__device__ __forceinline__ void mfma_core(
    const ushort* __restrict__ Ah, const ushort* __restrict__ Al,
    const float*  __restrict__ A0, const float*  __restrict__ A1,
    const float*  __restrict__ A2, const float*  __restrict__ A3, long ldA,
    const ushort* __restrict__ Bh, const ushort* __restrict__ Bl, long ldB,
    float* __restrict__ C, long ldC, const float* __restrict__ bias,
    ushort* __restrict__ Th, ushort* __restrict__ Tl, long ldT)
{
    __shared__ short lds[16384];   // 4 regions x 512 chunks x 8 shorts = 32 KB
    const int tid = threadIdx.x;
    const int i0 = tid, i1 = tid + 256;
    const int r0 = ((i0 >> 7) << 4) | (i0 & 15), r1 = ((i1 >> 7) << 4) | (i1 & 15);
    const int c0 = ((i0 >> 4) & 7) * 8,          c1 = ((i1 >> 4) & 7) * 8;
    const long a0o = (long)r0 * ldA + c0, a1o = (long)r1 * ldA + c1;
    const long b0o = (long)r0 * ldB + c0, b1o = (long)r1 * ldB + c1;

    int4 rah0, rah1, ral0, ral1, rbh0, rbh1, rbl0, rbl1;
    float fs0[8], fs1[8];

    auto issue_loads = [&](int it) {
        long off = (long)it * 64;
        if constexpr (ASRC == 4) {
            float4 a, b2;
            #pragma unroll
            for (int p = 0; p < 2; ++p) {
                float* d0 = fs0 + p * 4;
                float* d1 = fs1 + p * 4;
                a = *(const float4*)(A0 + a0o + off + p * 4);
                d0[0]=a.x; d0[1]=a.y; d0[2]=a.z; d0[3]=a.w;
                a = *(const float4*)(A1 + a0o + off + p * 4);
                d0[0]+=a.x; d0[1]+=a.y; d0[2]+=a.z; d0[3]+=a.w;
                a = *(const float4*)(A2 + a0o + off + p * 4);
                d0[0]+=a.x; d0[1]+=a.y; d0[2]+=a.z; d0[3]+=a.w;
                a = *(const float4*)(A3 + a0o + off + p * 4);
                d0[0]+=a.x; d0[1]+=a.y; d0[2]+=a.z; d0[3]+=a.w;
                b2 = *(const float4*)(A0 + a1o + off + p * 4);
                d1[0]=b2.x; d1[1]=b2.y; d1[2]=b2.z; d1[3]=b2.w;
                b2 = *(const float4*)(A1 + a1o + off + p * 4);
                d1[0]+=b2.x; d1[1]+=b2.y; d1[2]+=b2.z; d1[3]+=b2.w;
                b2 = *(const float4*)(A2 + a1o + off + p * 4);
                d1[0]+=b2.x; d1[1]+=b2.y; d1[2]+=b2.z; d1[3]+=b2.w;
                b2 = *(const float4*)(A3 + a1o + off + p * 4);
                d1[0]+=b2.x; d1[1]+=b2.y; d1[2]+=b2.z; d1[3]+=b2.w;
            }
        } else {
            rah0 = *(const int4*)(Ah + a0o + off); rah1 = *(const int4*)(Ah + a1o + off);
            ral0 = *(const int4*)(Al + a0o + off); ral1 = *(const int4*)(Al + a1o + off);
        }
        rbh0 = *(const int4*)(Bh + b0o + off); rbh1 = *(const int4*)(Bh + b1o + off);
        rbl0 = *(const int4*)(Bl + b0o + off); rbl1 = *(const int4*)(Bl + b1o + off);
    };
    auto write_lds = [&]() {
        if constexpr (ASRC == 4) {
            int4 h, l2;
            cvt8(fs0, h, l2);
            *(int4*)&lds[i0 * 8] = h; *(int4*)&lds[4096 + i0 * 8] = l2;
            cvt8(fs1, h, l2);
            *(int4*)&lds[i1 * 8] = h; *(int4*)&lds[4096 + i1 * 8] = l2;
        } else {
            *(int4*)&lds[i0 * 8] = rah0;        *(int4*)&lds[i1 * 8] = rah1;
            *(int4*)&lds[4096 + i0 * 8] = ral0; *(int4*)&lds[4096 + i1 * 8] = ral1;
        }
        *(int4*)&lds[8192  + i0 * 8] = rbh0; *(int4*)&lds[8192  + i1 * 8] = rbh1;
        *(int4*)&lds[12288 + i0 * 8] = rbl0; *(int4*)&lds[12288 + i1 * 8] = rbl1;
    };

    const int l = tid & 63, w = tid >> 6;
    const int ms = (w >> 1) * 2, ns = (w & 1) * 2;
    f32x4 acc00 = {0,0,0,0}, acc01 = {0,0,0,0}, acc10 = {0,0,0,0}, acc11 = {0,0,0,0};

    issue_loads(0);
    for (int it = 0; it < 4; ++it) {
        write_lds();
        __syncthreads();
        if (it < 3) issue_loads(it + 1);
        const int lo = l * 8;
        #pragma unroll
        for (int ks = 0; ks < 2; ++ks) {
            short8 a0h = *(const short8*)&lds[((ms    ) * 2 + ks) * 512 + lo];
            short8 a1h = *(const short8*)&lds[((ms + 1) * 2 + ks) * 512 + lo];
            short8 a0l = *(const short8*)&lds[4096 + ((ms    ) * 2 + ks) * 512 + lo];
            short8 a1l = *(const short8*)&lds[4096 + ((ms + 1) * 2 + ks) * 512 + lo];
            short8 b0h = *(const short8*)&lds[8192 + ((ns    ) * 2 + ks) * 512 + lo];
            short8 b1h = *(const short8*)&lds[8192 + ((ns + 1) * 2 + ks) * 512 + lo];
            short8 b0l = *(const short8*)&lds[12288 + ((ns    ) * 2 + ks) * 512 + lo];
            short8 b1l = *(const short8*)&lds[12288 + ((ns + 1) * 2 + ks) * 512 + lo];
            acc00 = MFMA(a0h, b0h, acc00); acc00 = MFMA(a0h, b0l, acc00); acc00 = MFMA(a0l, b0h, acc00);
            acc01 = MFMA(a0h, b1h, acc01); acc01 = MFMA(a0h, b1l, acc01); acc01 = MFMA(a0l, b1h, acc01);
            acc10 = MFMA(a1h, b0h, acc10); acc10 = MFMA(a1h, b0l, acc10); acc10 = MFMA(a1l, b0h, acc10);
            acc11 = MFMA(a1h, b1h, acc11); acc11 = MFMA(a1h, b1l, acc11); acc11 = MFMA(a1l, b1h, acc11);
        }
        __syncthreads();
    }

    auto epi = [&](int i, int j, f32x4 a) {
        const int n  = (ns + j) * 16 + (l & 15);
        const int mb = (ms + i) * 16 + (l >> 4) * 4;
        if constexpr (EPI == 1) {
            float bb = bias[n];
            float x0 = a.x + bb, x1 = a.y + bb, x2 = a.z + bb, x3 = a.w + bb;
            unsigned short h0 = bf16h(x0), h1 = bf16h(x1), h2 = bf16h(x2), h3 = bf16h(x3);
            int2 ph, pl;
            ph.x = (int)(h0 | ((unsigned)h1 << 16));
            ph.y = (int)(h2 | ((unsigned)h3 << 16));
            pl.x = (int)(bf16h(x0 - bf16f(h0)) | ((unsigned)bf16h(x1 - bf16f(h1)) << 16));
            pl.y = (int)(bf16h(x2 - bf16f(h2)) | ((unsigned)bf16h(x3 - bf16f(h3)) << 16));
            *(int2*)&Th[(long)n * ldT + mb] = ph;
            *(int2*)&Tl[(long)n * ldT + mb] = pl;
        } else {
            float bb = bias[n];
            float xs[4] = {a.x, a.y, a.z, a.w};
            #pragma unroll
            for (int r = 0; r < 4; ++r) {
                float x = xs[r] + bb;
                if constexpr (EPI == 0) x = exp2x_clamped(x);
                C[(long)(mb + r) * ldC + n] = x;
            }
        }
    };
    epi(0, 0, acc00); epi(0, 1, acc01); epi(1, 0, acc10); epi(1, 1, acc11);
}

// ---------------------------------------------------------------------------
// z=0: Eq=exp(2*(q@Wq^T+bq)); z=1: Ek likewise; z=2: vpT h/l (transposed bf16)
__global__ __launch_bounds__(256) void proj_mfma(
    const ushort* qh, const ushort* ql, const ushort* kh, const ushort* kl,
    const ushort* vh, const ushort* vl,
    const ushort* Wqh, const ushort* Wql, const ushort* Wkh, const ushort* Wkl,
    const ushort* Wvh, const ushort* Wvl,
    const float* bq, const float* bk, const float* bv,
    float* Eq, float* Ek, ushort* vpTh, ushort* vpTl)
{
    const int z = blockIdx.z;
    const long m0 = blockIdx.x * 64, n0 = blockIdx.y * 64;
    const ushort *Ah, *Al, *Bh, *Bl; const float* bias;
    if (z == 0)      { Ah = qh; Al = ql; Bh = Wqh; Bl = Wql; bias = bq; }
    else if (z == 1) { Ah = kh; Al = kl; Bh = Wkh; Bl = Wkl; bias = bk; }
    else             { Ah = vh; Al = vl; Bh = Wvh; Bl = Wvl; bias = bv; }
    Ah += m0 * 256; Al += m0 * 256; Bh += n0 * 256; Bl += n0 * 256; bias += n0;
    if (z < 2) {
        float* C = (z ? Ek : Eq) + m0 * 256 + n0;
        mfma_core<0, 0>(Ah, Al, nullptr, nullptr, nullptr, nullptr, 256,
                        Bh, Bl, 256, C, 256, bias, nullptr, nullptr, 0);
    } else {
        mfma_core<1, 0>(Ah, Al, nullptr, nullptr, nullptr, nullptr, 256,
                        Bh, Bl, 256, nullptr, 0, bias,
                        vpTh + n0 * 2048 + m0, vpTl + n0 * 2048 + m0, 2048);
    }
}

// ---------------------------------------------------------------------------
// scores + exp + row-sum atomics (softmax reduction fused, zero redundancy).
// score(q,k) = const - 2*sum_d w_d/(1+Eq_d*Ek_d); 4 d's share ONE rcp.
// Full d=256 per block (4 LDS chunk stages), 32q x 32k tile, 2q x 2k
// microtile. Grid 16x16x4 = 1024 blocks = 4 blocks/CU.
// NOTE: scores phase measured INVARIANT at ~36us across {1,2,4 blk/CU} x
// {2,3,4 B/elem-d} x {d-split 1,2,4} - at its mixed VALU/LDS/trans floor.
__global__ __launch_bounds__(256) void scores_kernel(
    const float* __restrict__ Eq, const float* __restrict__ Ek,
    const float* __restrict__ Ws, float* __restrict__ e_out,
    float* __restrict__ rowsum)
{
    __shared__ __align__(16) float qL[32][68];
    __shared__ __align__(16) float kL[32][68];
    const int b = blockIdx.z;
    const int q0 = blockIdx.x * 32, k0 = blockIdx.y * 32;
    const int tid = threadIdx.x;
    const int qi = tid >> 4, ki = tid & 15;

    float acc[2][2] = {};
    for (int cc = 0; cc < 4; ++cc) {
        const int c0 = cc * 64;
        const float* Eqb = Eq + ((long)b * SEQ + q0) * DM + c0;
        const float* Ekb = Ek + ((long)b * SEQ + k0) * DM + c0;
        if (cc) __syncthreads();
        #pragma unroll
        for (int i = 0; i < 2; ++i) {          // 32 rows x 64 d per side
            int f = i * 256 + tid;
            int r = f >> 4, col = (f & 15) << 2;
            *(float4*)&qL[r][col] = *(const float4*)(Eqb + (long)r * DM + col);
            *(float4*)&kL[r][col] = *(const float4*)(Ekb + (long)r * DM + col);
        }
        __syncthreads();
        #pragma unroll 2
        for (int d = 0; d < 64; d += 4) {
            float4 w4 = *(const float4*)(Ws + c0 + d);
            float4 av[2], bv[2];
            av[0] = *(const float4*)&qL[qi][d];
            av[1] = *(const float4*)&qL[qi + 16][d];
            bv[0] = *(const float4*)&kL[ki][d];
            bv[1] = *(const float4*)&kL[ki + 16][d];
            #pragma unroll
            for (int i = 0; i < 2; ++i)
                #pragma unroll
                for (int j = 0; j < 2; ++j) {
                    float xp = fmaf(av[i].x, bv[j].x, 1.0f);
                    float yp = fmaf(av[i].y, bv[j].y, 1.0f);
                    float zp = fmaf(av[i].z, bv[j].z, 1.0f);
                    float wp = fmaf(av[i].w, bv[j].w, 1.0f);
                    float xy = xp * yp, zw = zp * wp;
                    float n1 = fmaf(w4.x, yp, w4.y * xp);
                    float n2 = fmaf(w4.z, wp, w4.w * zp);
                    float num = fmaf(n1, zw, n2 * xy);
                    acc[i][j] = fmaf(num, __builtin_amdgcn_rcpf(xy * zw), acc[i][j]);
                }
        }
    }

    // e = exp(-2*acc); per-row partial sums over this block's 32 k-cols.
    constexpr float NL2E = -2.0f * 1.4426950408889634f;
    float rs[2];
    #pragma unroll
    for (int i = 0; i < 2; ++i) {
        float e0 = __builtin_amdgcn_exp2f(NL2E * acc[i][0]);
        float e1 = __builtin_amdgcn_exp2f(NL2E * acc[i][1]);
        acc[i][0] = e0; acc[i][1] = e1;
        float s = e0 + e1;
        s += __shfl_xor(s, 1); s += __shfl_xor(s, 2);
        s += __shfl_xor(s, 4); s += __shfl_xor(s, 8);
        rs[i] = s;
    }
    if (ki == 0) {
        atomicAdd(&rowsum[(long)b * SEQ + q0 + qi], rs[0]);
        atomicAdd(&rowsum[(long)b * SEQ + q0 + qi + 16], rs[1]);
    }

    float* pb = e_out + (long)b * SEQ * SEQ;
    #pragma unroll
    for (int i = 0; i < 2; ++i) {
        float* row = pb + (long)(q0 + qi + 16 * i) * SEQ + k0 + ki;
        row[0]  = acc[i][0];
        row[16] = acc[i][1];
    }
}

// ---------------------------------------------------------------------------
// FUSED attn@vp, h-split x4 (K=128/piece, 2 iters): grid 8(m) x 4(n) x
// 16(b*4+h) = 512 blocks = 2 blk/CU (was 256 = 1 blk/CU, latency-exposed).
// A = e (precomputed f32) staged with inline h/l cvt; inv_sum from rowsum.
// blockIdx.y==0 blocks emit f32 attn = e*inv for their K-quarter.
__global__ __launch_bounds__(256) void attnv_fused(
    const float* __restrict__ e_in, const float* __restrict__ rowsum,
    const ushort* __restrict__ vpTh, const ushort* __restrict__ vpTl,
    float* __restrict__ attn, float* __restrict__ attP)
{
    __shared__ short lds[16384];
    __shared__ float inv[64];
    const int z = blockIdx.z, b = z >> 2, h = z & 3;
    const long m0 = blockIdx.x * 64, n0 = blockIdx.y * 64;
    const int tid = threadIdx.x;

    if (tid < 64)
        inv[tid] = __builtin_amdgcn_rcpf(rowsum[(long)b * SEQ + m0 + tid]);
    __syncthreads();

    const int i0 = tid, i1 = tid + 256;
    const int r0 = ((i0 >> 7) << 4) | (i0 & 15), r1 = ((i1 >> 7) << 4) | (i1 & 15);
    const int c0 = ((i0 >> 4) & 7) * 8,          c1 = ((i1 >> 4) & 7) * 8;

    const ushort* Bh = vpTh + n0 * 2048 + (long)b * SEQ + h * 128;
    const ushort* Bl = vpTl + n0 * 2048 + (long)b * SEQ + h * 128;
    const long b0o = (long)r0 * 2048 + c0, b1o = (long)r1 * 2048 + c1;

    const float* pA = e_in + ((long)b * SEQ + m0) * SEQ + h * 128;
    float* attnW = (blockIdx.y == 0)
        ? attn + ((long)b * SEQ + m0) * SEQ + h * 128 : nullptr;

    int4 rbh0, rbh1, rbl0, rbl1;
    float e0[8], e1[8];

    auto issue = [&](int it) {
        long off = (long)it * 64;
        const float* q0p = pA + (long)r0 * SEQ + off + c0;
        const float* q1p = pA + (long)r1 * SEQ + off + c1;
        float4 x0 = *(const float4*)(q0p), x1 = *(const float4*)(q0p + 4);
        float4 u0 = *(const float4*)(q1p), u1 = *(const float4*)(q1p + 4);
        e0[0] = x0.x; e0[1] = x0.y; e0[2] = x0.z; e0[3] = x0.w;
        e0[4] = x1.x; e0[5] = x1.y; e0[6] = x1.z; e0[7] = x1.w;
        e1[0] = u0.x; e1[1] = u0.y; e1[2] = u0.z; e1[3] = u0.w;
        e1[4] = u1.x; e1[5] = u1.y; e1[6] = u1.z; e1[7] = u1.w;
        rbh0 = *(const int4*)(Bh + b0o + off); rbh1 = *(const int4*)(Bh + b1o + off);
        rbl0 = *(const int4*)(Bl + b0o + off); rbl1 = *(const int4*)(Bl + b1o + off);
    };
    auto writeL = [&](int it) {
        int4 hh, ll;
        cvt8(e0, hh, ll);
        *(int4*)&lds[i0 * 8] = hh; *(int4*)&lds[4096 + i0 * 8] = ll;
        cvt8(e1, hh, ll);
        *(int4*)&lds[i1 * 8] = hh; *(int4*)&lds[4096 + i1 * 8] = ll;
        *(int4*)&lds[8192  + i0 * 8] = rbh0; *(int4*)&lds[8192  + i1 * 8] = rbh1;
        *(int4*)&lds[12288 + i0 * 8] = rbl0; *(int4*)&lds[12288 + i1 * 8] = rbl1;
        if (attnW) {   // f32 attn output = e * inv_sum[row]
            long off = (long)it * 64;
            float iv0 = inv[r0], iv1 = inv[r1];
            float* w0 = attnW + (long)r0 * SEQ + off + c0;
            float* w1 = attnW + (long)r1 * SEQ + off + c1;
            float4 o;
            o.x = e0[0]*iv0; o.y = e0[1]*iv0; o.z = e0[2]*iv0; o.w = e0[3]*iv0;
            *(float4*)w0 = o;
            o.x = e0[4]*iv0; o.y = e0[5]*iv0; o.z = e0[6]*iv0; o.w = e0[7]*iv0;
            *(float4*)(w0 + 4) = o;
            o.x = e1[0]*iv1; o.y = e1[1]*iv1; o.z = e1[2]*iv1; o.w = e1[3]*iv1;
            *(float4*)w1 = o;
            o.x = e1[4]*iv1; o.y = e1[5]*iv1; o.z = e1[6]*iv1; o.w = e1[7]*iv1;
            *(float4*)(w1 + 4) = o;
        }
    };

    const int l = tid & 63, w = tid >> 6;
    const int ms = (w >> 1) * 2, ns = (w & 1) * 2;
    f32x4 acc00 = {0,0,0,0}, acc01 = {0,0,0,0}, acc10 = {0,0,0,0}, acc11 = {0,0,0,0};

    issue(0);
    for (int it = 0; it < 2; ++it) {
        writeL(it);
        __syncthreads();
        if (it < 1) issue(it + 1);
        const int lo = l * 8;
        #pragma unroll
        for (int ks = 0; ks < 2; ++ks) {
            short8 a0h = *(const short8*)&lds[((ms    ) * 2 + ks) * 512 + lo];
            short8 a1h = *(const short8*)&lds[((ms + 1) * 2 + ks) * 512 + lo];
            short8 a0l = *(const short8*)&lds[4096 + ((ms    ) * 2 + ks) * 512 + lo];
            short8 a1l = *(const short8*)&lds[4096 + ((ms + 1) * 2 + ks) * 512 + lo];
            short8 b0h = *(const short8*)&lds[8192 + ((ns    ) * 2 + ks) * 512 + lo];
            short8 b1h = *(const short8*)&lds[8192 + ((ns + 1) * 2 + ks) * 512 + lo];
            short8 b0l = *(const short8*)&lds[12288 + ((ns    ) * 2 + ks) * 512 + lo];
            short8 b1l = *(const short8*)&lds[12288 + ((ns + 1) * 2 + ks) * 512 + lo];
            acc00 = MFMA(a0h, b0h, acc00); acc00 = MFMA(a0h, b0l, acc00); acc00 = MFMA(a0l, b0h, acc00);
            acc01 = MFMA(a0h, b1h, acc01); acc01 = MFMA(a0h, b1l, acc01); acc01 = MFMA(a0l, b1h, acc01);
            acc10 = MFMA(a1h, b0h, acc10); acc10 = MFMA(a1h, b0l, acc10); acc10 = MFMA(a1l, b0h, acc10);
            acc11 = MFMA(a1h, b1h, acc11); acc11 = MFMA(a1h, b1l, acc11); acc11 = MFMA(a1l, b1h, acc11);
        }
        __syncthreads();
    }

    float* Cp = attP + (long)h * (BATCH * SEQ * DM) + ((long)b * SEQ + m0) * DM + n0;
    auto epi = [&](int i, int j, f32x4 a) {
        const int n  = (ns + j) * 16 + (l & 15);
        const int mb = (ms + i) * 16 + (l >> 4) * 4;
        float xs[4] = {a.x, a.y, a.z, a.w};
        #pragma unroll
        for (int r = 0; r < 4; ++r)
            Cp[(long)(mb + r) * DM + n] = xs[r] * inv[mb + r];
    };
    epi(0, 0, acc00); epi(0, 1, acc01); epi(1, 0, acc10); epi(1, 1, acc11);
}

// ---------------------------------------------------------------------------
// out = (att0+att1+att2+att3) @ Wo^T + bo  (4-way partial-sum in A staging)
__global__ __launch_bounds__(256) void out_mfma(
    const float* att0, const float* att1, const float* att2, const float* att3,
    const ushort* Woh, const ushort* Wol, const float* bo, float* out)
{
    const long m0 = blockIdx.x * 64, n0 = blockIdx.y * 64;
    mfma_core<2, 4>(nullptr, nullptr,
                    att0 + m0 * 256, att1 + m0 * 256,
                    att2 + m0 * 256, att3 + m0 * 256, 256,
                    Woh + n0 * 256, Wol + n0 * 256, 256,
                    out + m0 * 256 + n0, 256, bo + n0, nullptr, nullptr, 0);
}

// ---------------------------------------------------------------------------
extern "C" void kernel_launch(void* const* d_in, const int* in_sizes, int n_in,
                              void* d_out, int out_size, void* d_ws, size_t ws_size,
                              hipStream_t stream) {
    const float* query = (const float*)d_in[0];
    const float* key   = (const float*)d_in[1];
    const float* value = (const float*)d_in[2];
    const float* Wq = (const float*)d_in[3];
    const float* bq = (const float*)d_in[4];
    const float* Wk = (const float*)d_in[5];
    const float* bk = (const float*)d_in[6];
    const float* Wv = (const float*)d_in[7];
    const float* bv = (const float*)d_in[8];
    const float* Ws = (const float*)d_in[9];
    // d_in[10] = bs: unused (softmax shift-invariance)
    const float* Wo = (const float*)d_in[11];
    const float* bo = (const float*)d_in[12];

    float* out  = (float*)d_out;                              // (4,512,256)
    float* attn = (float*)d_out + (long)BATCH * SEQ * DM;     // (4,1,512,512)

    float* ws = (float*)d_ws;
    float* Eq     = ws;                      // 524288 f32
    float* Ek     = ws + 524288;
    float* e_buf  = ws + 1048576;            // 1048576 f32 (exp scores)
    float* attP   = ws + 2097152;            // 4 x 524288 f32 (h-quarter partials)
    float* rowsum = ws + 4194304;            // 2048 f32
    ushort* u = (ushort*)(ws + 4196352);
    ushort* qh  = u;              ushort* ql  = qh  + 524288;
    ushort* kh  = ql  + 524288;   ushort* kl  = kh  + 524288;
    ushort* vh  = kl  + 524288;   ushort* vl  = vh  + 524288;
    ushort* Wqh = vl  + 524288;   ushort* Wql = Wqh + 65536;
    ushort* Wkh = Wql + 65536;    ushort* Wkl = Wkh + 65536;
    ushort* Wvh = Wkl + 65536;    ushort* Wvl = Wvh + 65536;
    ushort* Woh = Wvl + 65536;    ushort* Wol = Woh + 65536;
    ushort* vpTh = Wol + 65536;   ushort* vpTl = vpTh + 524288;

    conv_kernel  <<<dim3(256, 8),    256, 0, stream>>>(query, key, value, Wq, Wk, Wv, Wo,
                                                       qh, ql, kh, kl, vh, vl,
                                                       Wqh, Wql, Wkh, Wkl, Wvh, Wvl, Woh, Wol,
                                                       rowsum);
    proj_mfma    <<<dim3(32, 4, 3),  256, 0, stream>>>(qh, ql, kh, kl, vh, vl,
                                                       Wqh, Wql, Wkh, Wkl, Wvh, Wvl,
                                                       bq, bk, bv, Eq, Ek, vpTh, vpTl);
    scores_kernel<<<dim3(16, 16, 4), 256, 0, stream>>>(Eq, Ek, Ws, e_buf, rowsum);
    attnv_fused  <<<dim3(8, 4, 16),  256, 0, stream>>>(e_buf, rowsum, vpTh, vpTl,
                                                       attn, attP);
    out_mfma     <<<dim3(32, 4),     256, 0, stream>>>(attP, attP + 524288,
                                                       attP + 1048576, attP + 1572864,
                                                       Woh, Wol, bo, out);
}

// Round 15
// 67.823 us; speedup vs baseline: 1.0509x; 1.0509x over previous
//
#include <hip/hip_runtime.h>

typedef __attribute__((ext_vector_type(8))) short short8;
typedef __attribute__((ext_vector_type(4))) float f32x4;

constexpr int BATCH = 4;
constexpr int SEQ   = 512;
constexpr int DM    = 256;

#define MFMA(a,b,c) __builtin_amdgcn_mfma_f32_16x16x32_bf16((a),(b),(c),0,0,0)

// ---------------------------------------------------------------------------
__device__ __forceinline__ unsigned short bf16h(float x) {
    unsigned u = __float_as_uint(x);
    return (unsigned short)((u + 0x7FFF + ((u >> 16) & 1)) >> 16);  // RNE
}
__device__ __forceinline__ float bf16f(unsigned short h) {
    return __uint_as_float(((unsigned)h) << 16);
}
__device__ __forceinline__ float exp2x_clamped(float x) {
    x = fminf(5.0f, fmaxf(-5.0f, x));
    return __builtin_amdgcn_exp2f(x * 2.8853900817779268f); // exp(2x)
}
__device__ __forceinline__ void cvt8(const float* s, int4& h, int4& l) {
    unsigned hw[8], lw[8];
    #pragma unroll
    for (int j = 0; j < 8; ++j) {
        unsigned short hb = bf16h(s[j]);
        hw[j] = hb;
        lw[j] = bf16h(s[j] - bf16f(hb));
    }
    h.x = (int)(hw[0] | (hw[1] << 16)); h.y = (int)(hw[2] | (hw[3] << 16));
    h.z = (int)(hw[4] | (hw[5] << 16)); h.w = (int)(hw[6] | (hw[7] << 16));
    l.x = (int)(lw[0] | (lw[1] << 16)); l.y = (int)(lw[2] | (lw[3] << 16));
    l.z = (int)(lw[4] | (lw[5] << 16)); l.w = (int)(lw[6] | (lw[7] << 16));
}

// ---------------------------------------------------------------------------
// f32 -> bf16 hi/lo pre-conversion for q,k,v and the 4 weight matrices,
// plus (y==7) zeroing of the 2048-entry rowsum accumulator (every call,
// graph-replay safe).
__global__ __launch_bounds__(256) void conv_kernel(
    const float* __restrict__ q, const float* __restrict__ k, const float* __restrict__ v,
    const float* __restrict__ Wq, const float* __restrict__ Wk,
    const float* __restrict__ Wv, const float* __restrict__ Wo,
    ushort* qh, ushort* ql, ushort* kh, ushort* kl, ushort* vh, ushort* vl,
    ushort* Wqh, ushort* Wql, ushort* Wkh, ushort* Wkl,
    ushort* Wvh, ushort* Wvl, ushort* Woh, ushort* Wol,
    float* rowsum)
{
    if (blockIdx.y == 7) {
        int idx = blockIdx.x * 256 + threadIdx.x;
        if (idx < BATCH * SEQ) rowsum[idx] = 0.f;
        return;
    }
    const float* s; ushort* h; ushort* l; int n;
    switch (blockIdx.y) {
        case 0: s = q;  h = qh;  l = ql;  n = 524288; break;
        case 1: s = k;  h = kh;  l = kl;  n = 524288; break;
        case 2: s = v;  h = vh;  l = vl;  n = 524288; break;
        case 3: s = Wq; h = Wqh; l = Wql; n = 65536;  break;
        case 4: s = Wk; h = Wkh; l = Wkl; n = 65536;  break;
        case 5: s = Wv; h = Wvh; l = Wvl; n = 65536;  break;
        default:s = Wo; h = Woh; l = Wol; n = 65536;  break;
    }
    int idx = (blockIdx.x * 256 + threadIdx.x) * 8;
    if (idx >= n) return;
    float4 f0 = *(const float4*)(s + idx);
    float4 f1 = *(const float4*)(s + idx + 4);
    float xs[8] = {f0.x, f0.y, f0.z, f0.w, f1.x, f1.y, f1.z, f1.w};
    int4 ph, pl;
    cvt8(xs, ph, pl);
    *(int4*)&h[idx] = ph;
    *(int4*)&l[idx] = pl;
}

// ---------------------------------------------------------------------------
// MFMA GEMM core (round-5 proven single-buffer structure), K=256 fixed.
// C[m][n] = sum_k A[m][k]*B[n][k]; f32 as bf16 hi/lo, 3 passes (hh+hl+lh).
// Tile 64x64, 4 waves (2x2), LDS frag-linear chunk order.
// EPI: 0 = f32 C = exp(2(x+bias)); 1 = bf16 h/l TRANSPOSED out (+bias);
//      2 = f32 C = x + bias.
// ASRC: 0 = A from bf16 h/l; 2 = A from sum of two f32 arrays (inline cvt).
template<int EPI, int ASRC>
__device__ __forceinline__ void mfma_core(
    const ushort* __restrict__ Ah, const ushort* __restrict__ Al,
    const float*  __restrict__ A0, const float*  __restrict__ A1, long ldA,
    const ushort* __restrict__ Bh, const ushort* __restrict__ Bl, long ldB,
    float* __restrict__ C, long ldC, const float* __restrict__ bias,
    ushort* __restrict__ Th, ushort* __restrict__ Tl, long ldT)
{
    __shared__ short lds[16384];   // 4 regions x 512 chunks x 8 shorts = 32 KB
    const int tid = threadIdx.x;
    const int i0 = tid, i1 = tid + 256;
    const int r0 = ((i0 >> 7) << 4) | (i0 & 15), r1 = ((i1 >> 7) << 4) | (i1 & 15);
    const int c0 = ((i0 >> 4) & 7) * 8,          c1 = ((i1 >> 4) & 7) * 8;
    const long a0o = (long)r0 * ldA + c0, a1o = (long)r1 * ldA + c1;
    const long b0o = (long)r0 * ldB + c0, b1o = (long)r1 * ldB + c1;

    int4 rah0, rah1, ral0, ral1, rbh0, rbh1, rbl0, rbl1;
    float4 fa00, fa01, fa10, fa11, ga00, ga01, ga10, ga11;

    auto issue_loads = [&](int it) {
        long off = (long)it * 64;
        if constexpr (ASRC == 2) {
            fa00 = *(const float4*)(A0 + a0o + off); fa01 = *(const float4*)(A0 + a0o + off + 4);
            fa10 = *(const float4*)(A0 + a1o + off); fa11 = *(const float4*)(A0 + a1o + off + 4);
            ga00 = *(const float4*)(A1 + a0o + off); ga01 = *(const float4*)(A1 + a0o + off + 4);
            ga10 = *(const float4*)(A1 + a1o + off); ga11 = *(const float4*)(A1 + a1o + off + 4);
        } else {
            rah0 = *(const int4*)(Ah + a0o + off); rah1 = *(const int4*)(Ah + a1o + off);
            ral0 = *(const int4*)(Al + a0o + off); ral1 = *(const int4*)(Al + a1o + off);
        }
        rbh0 = *(const int4*)(Bh + b0o + off); rbh1 = *(const int4*)(Bh + b1o + off);
        rbl0 = *(const int4*)(Bl + b0o + off); rbl1 = *(const int4*)(Bl + b1o + off);
    };
    auto write_lds = [&]() {
        if constexpr (ASRC == 2) {
            float s0[8] = {fa00.x+ga00.x, fa00.y+ga00.y, fa00.z+ga00.z, fa00.w+ga00.w,
                           fa01.x+ga01.x, fa01.y+ga01.y, fa01.z+ga01.z, fa01.w+ga01.w};
            float s1[8] = {fa10.x+ga10.x, fa10.y+ga10.y, fa10.z+ga10.z, fa10.w+ga10.w,
                           fa11.x+ga11.x, fa11.y+ga11.y, fa11.z+ga11.z, fa11.w+ga11.w};
            int4 h, l2;
            cvt8(s0, h, l2);
            *(int4*)&lds[i0 * 8] = h; *(int4*)&lds[4096 + i0 * 8] = l2;
            cvt8(s1, h, l2);
            *(int4*)&lds[i1 * 8] = h; *(int4*)&lds[4096 + i1 * 8] = l2;
        } else {
            *(int4*)&lds[i0 * 8] = rah0;        *(int4*)&lds[i1 * 8] = rah1;
            *(int4*)&lds[4096 + i0 * 8] = ral0; *(int4*)&lds[4096 + i1 * 8] = ral1;
        }
        *(int4*)&lds[8192  + i0 * 8] = rbh0; *(int4*)&lds[8192  + i1 * 8] = rbh1;
        *(int4*)&lds[12288 + i0 * 8] = rbl0; *(int4*)&lds[12288 + i1 * 8] = rbl1;
    };

    const int l = tid & 63, w = tid >> 6;
    const int ms = (w >> 1) * 2, ns = (w & 1) * 2;
    f32x4 acc00 = {0,0,0,0}, acc01 = {0,0,0,0}, acc10 = {0,0,0,0}, acc11 = {0,0,0,0};

    issue_loads(0);
    for (int it = 0; it < 4; ++it) {
        write_lds();
        __syncthreads();
        if (it < 3) issue_loads(it + 1);
        const int lo = l * 8;
        #pragma unroll
        for (int ks = 0; ks < 2; ++ks) {
            short8 a0h = *(const short8*)&lds[((ms    ) * 2 + ks) * 512 + lo];
            short8 a1h = *(const short8*)&lds[((ms + 1) * 2 + ks) * 512 + lo];
            short8 a0l = *(const short8*)&lds[4096 + ((ms    ) * 2 + ks) * 512 + lo];
            short8 a1l = *(const short8*)&lds[4096 + ((ms + 1) * 2 + ks) * 512 + lo];
            short8 b0h = *(const short8*)&lds[8192 + ((ns    ) * 2 + ks) * 512 + lo];
            short8 b1h = *(const short8*)&lds[8192 + ((ns + 1) * 2 + ks) * 512 + lo];
            short8 b0l = *(const short8*)&lds[12288 + ((ns    ) * 2 + ks) * 512 + lo];
            short8 b1l = *(const short8*)&lds[12288 + ((ns + 1) * 2 + ks) * 512 + lo];
            acc00 = MFMA(a0h, b0h, acc00); acc00 = MFMA(a0h, b0l, acc00); acc00 = MFMA(a0l, b0h, acc00);
            acc01 = MFMA(a0h, b1h, acc01); acc01 = MFMA(a0h, b1l, acc01); acc01 = MFMA(a0l, b1h, acc01);
            acc10 = MFMA(a1h, b0h, acc10); acc10 = MFMA(a1h, b0l, acc10); acc10 = MFMA(a1l, b0h, acc10);
            acc11 = MFMA(a1h, b1h, acc11); acc11 = MFMA(a1h, b1l, acc11); acc11 = MFMA(a1l, b1h, acc11);
        }
        __syncthreads();
    }

    auto epi = [&](int i, int j, f32x4 a) {
        const int n  = (ns + j) * 16 + (l & 15);
        const int mb = (ms + i) * 16 + (l >> 4) * 4;
        if constexpr (EPI == 1) {
            float bb = bias[n];
            float x0 = a.x + bb, x1 = a.y + bb, x2 = a.z + bb, x3 = a.w + bb;
            unsigned short h0 = bf16h(x0), h1 = bf16h(x1), h2 = bf16h(x2), h3 = bf16h(x3);
            int2 ph, pl;
            ph.x = (int)(h0 | ((unsigned)h1 << 16));
            ph.y = (int)(h2 | ((unsigned)h3 << 16));
            pl.x = (int)(bf16h(x0 - bf16f(h0)) | ((unsigned)bf16h(x1 - bf16f(h1)) << 16));
            pl.y = (int)(bf16h(x2 - bf16f(h2)) | ((unsigned)bf16h(x3 - bf16f(h3)) << 16));
            *(int2*)&Th[(long)n * ldT + mb] = ph;
            *(int2*)&Tl[(long)n * ldT + mb] = pl;
        } else {
            float bb = bias[n];
            float xs[4] = {a.x, a.y, a.z, a.w};
            #pragma unroll
            for (int r = 0; r < 4; ++r) {
                float x = xs[r] + bb;
                if constexpr (EPI == 0) x = exp2x_clamped(x);
                C[(long)(mb + r) * ldC + n] = x;
            }
        }
    };
    epi(0, 0, acc00); epi(0, 1, acc01); epi(1, 0, acc10); epi(1, 1, acc11);
}

// ---------------------------------------------------------------------------
// z=0: Eq=exp(2*(q@Wq^T+bq)); z=1: Ek likewise; z=2: vpT h/l (transposed bf16)
__global__ __launch_bounds__(256) void proj_mfma(
    const ushort* qh, const ushort* ql, const ushort* kh, const ushort* kl,
    const ushort* vh, const ushort* vl,
    const ushort* Wqh, const ushort* Wql, const ushort* Wkh, const ushort* Wkl,
    const ushort* Wvh, const ushort* Wvl,
    const float* bq, const float* bk, const float* bv,
    float* Eq, float* Ek, ushort* vpTh, ushort* vpTl)
{
    const int z = blockIdx.z;
    const long m0 = blockIdx.x * 64, n0 = blockIdx.y * 64;
    const ushort *Ah, *Al, *Bh, *Bl; const float* bias;
    if (z == 0)      { Ah = qh; Al = ql; Bh = Wqh; Bl = Wql; bias = bq; }
    else if (z == 1) { Ah = kh; Al = kl; Bh = Wkh; Bl = Wkl; bias = bk; }
    else             { Ah = vh; Al = vl; Bh = Wvh; Bl = Wvl; bias = bv; }
    Ah += m0 * 256; Al += m0 * 256; Bh += n0 * 256; Bl += n0 * 256; bias += n0;
    if (z < 2) {
        float* C = (z ? Ek : Eq) + m0 * 256 + n0;
        mfma_core<0, 0>(Ah, Al, nullptr, nullptr, 256, Bh, Bl, 256,
                        C, 256, bias, nullptr, nullptr, 0);
    } else {
        mfma_core<1, 0>(Ah, Al, nullptr, nullptr, 256, Bh, Bl, 256,
                        nullptr, 0, bias,
                        vpTh + n0 * 2048 + m0, vpTl + n0 * 2048 + m0, 2048);
    }
}

// ---------------------------------------------------------------------------
// scores + exp + row-sum atomics (softmax reduction fused, zero redundancy).
// score(q,k) = const - 2*sum_d w_d/(1+Eq_d*Ek_d); 4 d's share ONE rcp.
// Full d=256 per block (4 LDS chunk stages), 32q x 32k tile, 2q x 2k
// microtile. Grid 16x16x4 = 1024 blocks = 4 blocks/CU.
// NOTE: scores phase measured INVARIANT at ~36us across {1,2,4 blk/CU} x
// {2,3,4 B/elem-d} x {d-split 1,2,4} - at its mixed VALU/LDS/trans floor
// (VALU-issue ~15us and LDS-b128 ~15us per CU effectively serialize).
__global__ __launch_bounds__(256) void scores_kernel(
    const float* __restrict__ Eq, const float* __restrict__ Ek,
    const float* __restrict__ Ws, float* __restrict__ e_out,
    float* __restrict__ rowsum)
{
    __shared__ __align__(16) float qL[32][68];
    __shared__ __align__(16) float kL[32][68];
    const int b = blockIdx.z;
    const int q0 = blockIdx.x * 32, k0 = blockIdx.y * 32;
    const int tid = threadIdx.x;
    const int qi = tid >> 4, ki = tid & 15;

    float acc[2][2] = {};
    for (int cc = 0; cc < 4; ++cc) {
        const int c0 = cc * 64;
        const float* Eqb = Eq + ((long)b * SEQ + q0) * DM + c0;
        const float* Ekb = Ek + ((long)b * SEQ + k0) * DM + c0;
        if (cc) __syncthreads();
        #pragma unroll
        for (int i = 0; i < 2; ++i) {          // 32 rows x 64 d per side
            int f = i * 256 + tid;
            int r = f >> 4, col = (f & 15) << 2;
            *(float4*)&qL[r][col] = *(const float4*)(Eqb + (long)r * DM + col);
            *(float4*)&kL[r][col] = *(const float4*)(Ekb + (long)r * DM + col);
        }
        __syncthreads();
        #pragma unroll 2
        for (int d = 0; d < 64; d += 4) {
            float4 w4 = *(const float4*)(Ws + c0 + d);
            float4 av[2], bv[2];
            av[0] = *(const float4*)&qL[qi][d];
            av[1] = *(const float4*)&qL[qi + 16][d];
            bv[0] = *(const float4*)&kL[ki][d];
            bv[1] = *(const float4*)&kL[ki + 16][d];
            #pragma unroll
            for (int i = 0; i < 2; ++i)
                #pragma unroll
                for (int j = 0; j < 2; ++j) {
                    float xp = fmaf(av[i].x, bv[j].x, 1.0f);
                    float yp = fmaf(av[i].y, bv[j].y, 1.0f);
                    float zp = fmaf(av[i].z, bv[j].z, 1.0f);
                    float wp = fmaf(av[i].w, bv[j].w, 1.0f);
                    float xy = xp * yp, zw = zp * wp;
                    float n1 = fmaf(w4.x, yp, w4.y * xp);
                    float n2 = fmaf(w4.z, wp, w4.w * zp);
                    float num = fmaf(n1, zw, n2 * xy);
                    acc[i][j] = fmaf(num, __builtin_amdgcn_rcpf(xy * zw), acc[i][j]);
                }
        }
    }

    // e = exp(-2*acc); per-row partial sums over this block's 32 k-cols.
    constexpr float NL2E = -2.0f * 1.4426950408889634f;
    float rs[2];
    #pragma unroll
    for (int i = 0; i < 2; ++i) {
        float e0 = __builtin_amdgcn_exp2f(NL2E * acc[i][0]);
        float e1 = __builtin_amdgcn_exp2f(NL2E * acc[i][1]);
        acc[i][0] = e0; acc[i][1] = e1;
        float s = e0 + e1;
        s += __shfl_xor(s, 1); s += __shfl_xor(s, 2);
        s += __shfl_xor(s, 4); s += __shfl_xor(s, 8);
        rs[i] = s;
    }
    if (ki == 0) {
        atomicAdd(&rowsum[(long)b * SEQ + q0 + qi], rs[0]);
        atomicAdd(&rowsum[(long)b * SEQ + q0 + qi + 16], rs[1]);
    }

    float* pb = e_out + (long)b * SEQ * SEQ;
    #pragma unroll
    for (int i = 0; i < 2; ++i) {
        float* row = pb + (long)(q0 + qi + 16 * i) * SEQ + k0 + ki;
        row[0]  = acc[i][0];
        row[16] = acc[i][1];
    }
}

// ---------------------------------------------------------------------------
// FUSED attn@vp: A = e (precomputed, f32) staged with inline h/l cvt;
// inv_sum from rowsum (64 loads + rcp, no scan). Epilogue scales by inv.
// blockIdx.y==0 blocks also emit f32 attn = e*inv for their K-half.
// Grid 8(m) x 4(n) x 8(b*2+h) = 256 blocks. (h-split x4 measured WORSE:
// r14 +3.3us - K=128/block too short, partial traffic dominates.)
__global__ __launch_bounds__(256) void attnv_fused(
    const float* __restrict__ e_in, const float* __restrict__ rowsum,
    const ushort* __restrict__ vpTh, const ushort* __restrict__ vpTl,
    float* __restrict__ attn, float* __restrict__ att0, float* __restrict__ att1)
{
    __shared__ short lds[16384];
    __shared__ float inv[64];
    const int z = blockIdx.z, b = z >> 1, h = z & 1;
    const long m0 = blockIdx.x * 64, n0 = blockIdx.y * 64;
    const int tid = threadIdx.x;

    if (tid < 64)
        inv[tid] = __builtin_amdgcn_rcpf(rowsum[(long)b * SEQ + m0 + tid]);
    __syncthreads();

    const int i0 = tid, i1 = tid + 256;
    const int r0 = ((i0 >> 7) << 4) | (i0 & 15), r1 = ((i1 >> 7) << 4) | (i1 & 15);
    const int c0 = ((i0 >> 4) & 7) * 8,          c1 = ((i1 >> 4) & 7) * 8;

    const ushort* Bh = vpTh + n0 * 2048 + (long)b * SEQ + h * 256;
    const ushort* Bl = vpTl + n0 * 2048 + (long)b * SEQ + h * 256;
    const long b0o = (long)r0 * 2048 + c0, b1o = (long)r1 * 2048 + c1;

    const float* pA = e_in + ((long)b * SEQ + m0) * SEQ + h * 256;
    float* attnW = (blockIdx.y == 0)
        ? attn + ((long)b * SEQ + m0) * SEQ + h * 256 : nullptr;

    int4 rbh0, rbh1, rbl0, rbl1;
    float e0[8], e1[8];

    auto issue = [&](int it) {
        long off = (long)it * 64;
        const float* q0p = pA + (long)r0 * SEQ + off + c0;
        const float* q1p = pA + (long)r1 * SEQ + off + c1;
        float4 x0 = *(const float4*)(q0p), x1 = *(const float4*)(q0p + 4);
        float4 u0 = *(const float4*)(q1p), u1 = *(const float4*)(q1p + 4);
        e0[0] = x0.x; e0[1] = x0.y; e0[2] = x0.z; e0[3] = x0.w;
        e0[4] = x1.x; e0[5] = x1.y; e0[6] = x1.z; e0[7] = x1.w;
        e1[0] = u0.x; e1[1] = u0.y; e1[2] = u0.z; e1[3] = u0.w;
        e1[4] = u1.x; e1[5] = u1.y; e1[6] = u1.z; e1[7] = u1.w;
        rbh0 = *(const int4*)(Bh + b0o + off); rbh1 = *(const int4*)(Bh + b1o + off);
        rbl0 = *(const int4*)(Bl + b0o + off); rbl1 = *(const int4*)(Bl + b1o + off);
    };
    auto writeL = [&](int it) {
        int4 hh, ll;
        cvt8(e0, hh, ll);
        *(int4*)&lds[i0 * 8] = hh; *(int4*)&lds[4096 + i0 * 8] = ll;
        cvt8(e1, hh, ll);
        *(int4*)&lds[i1 * 8] = hh; *(int4*)&lds[4096 + i1 * 8] = ll;
        *(int4*)&lds[8192  + i0 * 8] = rbh0; *(int4*)&lds[8192  + i1 * 8] = rbh1;
        *(int4*)&lds[12288 + i0 * 8] = rbl0; *(int4*)&lds[12288 + i1 * 8] = rbl1;
        if (attnW) {   // f32 attn output = e * inv_sum[row]
            long off = (long)it * 64;
            float iv0 = inv[r0], iv1 = inv[r1];
            float* w0 = attnW + (long)r0 * SEQ + off + c0;
            float* w1 = attnW + (long)r1 * SEQ + off + c1;
            float4 o;
            o.x = e0[0]*iv0; o.y = e0[1]*iv0; o.z = e0[2]*iv0; o.w = e0[3]*iv0;
            *(float4*)w0 = o;
            o.x = e0[4]*iv0; o.y = e0[5]*iv0; o.z = e0[6]*iv0; o.w = e0[7]*iv0;
            *(float4*)(w0 + 4) = o;
            o.x = e1[0]*iv1; o.y = e1[1]*iv1; o.z = e1[2]*iv1; o.w = e1[3]*iv1;
            *(float4*)w1 = o;
            o.x = e1[4]*iv1; o.y = e1[5]*iv1; o.z = e1[6]*iv1; o.w = e1[7]*iv1;
            *(float4*)(w1 + 4) = o;
        }
    };

    const int l = tid & 63, w = tid >> 6;
    const int ms = (w >> 1) * 2, ns = (w & 1) * 2;
    f32x4 acc00 = {0,0,0,0}, acc01 = {0,0,0,0}, acc10 = {0,0,0,0}, acc11 = {0,0,0,0};

    issue(0);
    for (int it = 0; it < 4; ++it) {
        writeL(it);
        __syncthreads();
        if (it < 3) issue(it + 1);
        const int lo = l * 8;
        #pragma unroll
        for (int ks = 0; ks < 2; ++ks) {
            short8 a0h = *(const short8*)&lds[((ms    ) * 2 + ks) * 512 + lo];
            short8 a1h = *(const short8*)&lds[((ms + 1) * 2 + ks) * 512 + lo];
            short8 a0l = *(const short8*)&lds[4096 + ((ms    ) * 2 + ks) * 512 + lo];
            short8 a1l = *(const short8*)&lds[4096 + ((ms + 1) * 2 + ks) * 512 + lo];
            short8 b0h = *(const short8*)&lds[8192 + ((ns    ) * 2 + ks) * 512 + lo];
            short8 b1h = *(const short8*)&lds[8192 + ((ns + 1) * 2 + ks) * 512 + lo];
            short8 b0l = *(const short8*)&lds[12288 + ((ns    ) * 2 + ks) * 512 + lo];
            short8 b1l = *(const short8*)&lds[12288 + ((ns + 1) * 2 + ks) * 512 + lo];
            acc00 = MFMA(a0h, b0h, acc00); acc00 = MFMA(a0h, b0l, acc00); acc00 = MFMA(a0l, b0h, acc00);
            acc01 = MFMA(a0h, b1h, acc01); acc01 = MFMA(a0h, b1l, acc01); acc01 = MFMA(a0l, b1h, acc01);
            acc10 = MFMA(a1h, b0h, acc10); acc10 = MFMA(a1h, b0l, acc10); acc10 = MFMA(a1l, b0h, acc10);
            acc11 = MFMA(a1h, b1h, acc11); acc11 = MFMA(a1h, b1l, acc11); acc11 = MFMA(a1l, b1h, acc11);
        }
        __syncthreads();
    }

    float* Cp = (h ? att1 : att0) + ((long)b * SEQ + m0) * DM + n0;
    auto epi = [&](int i, int j, f32x4 a) {
        const int n  = (ns + j) * 16 + (l & 15);
        const int mb = (ms + i) * 16 + (l >> 4) * 4;
        float xs[4] = {a.x, a.y, a.z, a.w};
        #pragma unroll
        for (int r = 0; r < 4; ++r)
            Cp[(long)(mb + r) * DM + n] = xs[r] * inv[mb + r];
    };
    epi(0, 0, acc00); epi(0, 1, acc01); epi(1, 0, acc10); epi(1, 1, acc11);
}

// ---------------------------------------------------------------------------
// out = (att0+att1) @ Wo^T + bo  (partial-sum fused into A staging)
__global__ __launch_bounds__(256) void out_mfma(
    const float* att0, const float* att1,
    const ushort* Woh, const ushort* Wol, const float* bo, float* out)
{
    const long m0 = blockIdx.x * 64, n0 = blockIdx.y * 64;
    mfma_core<2, 2>(nullptr, nullptr, att0 + m0 * 256, att1 + m0 * 256, 256,
                    Woh + n0 * 256, Wol + n0 * 256, 256,
                    out + m0 * 256 + n0, 256, bo + n0, nullptr, nullptr, 0);
}

// ---------------------------------------------------------------------------
extern "C" void kernel_launch(void* const* d_in, const int* in_sizes, int n_in,
                              void* d_out, int out_size, void* d_ws, size_t ws_size,
                              hipStream_t stream) {
    const float* query = (const float*)d_in[0];
    const float* key   = (const float*)d_in[1];
    const float* value = (const float*)d_in[2];
    const float* Wq = (const float*)d_in[3];
    const float* bq = (const float*)d_in[4];
    const float* Wk = (const float*)d_in[5];
    const float* bk = (const float*)d_in[6];
    const float* Wv = (const float*)d_in[7];
    const float* bv = (const float*)d_in[8];
    const float* Ws = (const float*)d_in[9];
    // d_in[10] = bs: unused (softmax shift-invariance)
    const float* Wo = (const float*)d_in[11];
    const float* bo = (const float*)d_in[12];

    float* out  = (float*)d_out;                              // (4,512,256)
    float* attn = (float*)d_out + (long)BATCH * SEQ * DM;     // (4,1,512,512)

    float* ws = (float*)d_ws;
    float* Eq     = ws;                      // 524288 f32
    float* Ek     = ws + 524288;
    float* e_buf  = ws + 1048576;            // 1048576 f32 (exp scores)
    float* att0   = ws + 2097152;            // 524288 f32
    float* att1   = ws + 2621440;            // 524288 f32
    float* rowsum = ws + 3145728;            // 2048 f32
    ushort* u = (ushort*)(ws + 3147776);
    ushort* qh  = u;              ushort* ql  = qh  + 524288;
    ushort* kh  = ql  + 524288;   ushort* kl  = kh  + 524288;
    ushort* vh  = kl  + 524288;   ushort* vl  = vh  + 524288;
    ushort* Wqh = vl  + 524288;   ushort* Wql = Wqh + 65536;
    ushort* Wkh = Wql + 65536;    ushort* Wkl = Wkh + 65536;
    ushort* Wvh = Wkl + 65536;    ushort* Wvl = Wvh + 65536;
    ushort* Woh = Wvl + 65536;    ushort* Wol = Woh + 65536;
    ushort* vpTh = Wol + 65536;   ushort* vpTl = vpTh + 524288;

    conv_kernel  <<<dim3(256, 8),    256, 0, stream>>>(query, key, value, Wq, Wk, Wv, Wo,
                                                       qh, ql, kh, kl, vh, vl,
                                                       Wqh, Wql, Wkh, Wkl, Wvh, Wvl, Woh, Wol,
                                                       rowsum);
    proj_mfma    <<<dim3(32, 4, 3),  256, 0, stream>>>(qh, ql, kh, kl, vh, vl,
                                                       Wqh, Wql, Wkh, Wkl, Wvh, Wvl,
                                                       bq, bk, bv, Eq, Ek, vpTh, vpTl);
    scores_kernel<<<dim3(16, 16, 4), 256, 0, stream>>>(Eq, Ek, Ws, e_buf, rowsum);
    attnv_fused  <<<dim3(8, 4, 8),   256, 0, stream>>>(e_buf, rowsum, vpTh, vpTl,
                                                       attn, att0, att1);
    out_mfma     <<<dim3(32, 4),     256, 0, stream>>>(att0, att1, Woh, Wol, bo, out);
}